// Round 6
// baseline (2227.811 us; speedup 1.0000x reference)
//
#include <hip/hip_runtime.h>
#include <hip/hip_bf16.h>
#include <math.h>

#define DIN 128
#define DH 256
#define DOUT 128
#define NLAYERS 8
#define EPSLN 1e-5f

typedef __hip_bfloat16 bf16;
typedef __attribute__((ext_vector_type(8))) short short8;
typedef __attribute__((ext_vector_type(4))) short short4v;
typedef __attribute__((ext_vector_type(2))) short short2v;
typedef __attribute__((ext_vector_type(4))) float f32x4;

__device__ __forceinline__ float ldf(const void* p, size_t idx, int isbf) {
    if (isbf) return __bfloat162float(((const bf16*)p)[idx]);
    return ((const float*)p)[idx];
}
__device__ __forceinline__ short f2s(float v) {
    bf16 b = __float2bfloat16(v);
    return *reinterpret_cast<short*>(&b);
}
__device__ __forceinline__ float s2f(short s) {
    unsigned int u = ((unsigned int)(unsigned short)s) << 16;
    float f;
    __builtin_memcpy(&f, &u, 4);
    return f;
}
__device__ __forceinline__ void gl_lds16(const void* g, void* l) {
    __builtin_amdgcn_global_load_lds(
        (const __attribute__((address_space(1))) unsigned int*)g,
        (__attribute__((address_space(3))) unsigned int*)l,
        16, 0, 0);
}

// ---------------- dtype probe ----------------
__global__ void k_detect(const unsigned int* __restrict__ xw, int* __restrict__ flag) {
    __shared__ int cnt;
    if (threadIdx.x == 0) cnt = 0;
    __syncthreads();
    unsigned int w = xw[threadIdx.x];
    int e = (w >> 7) & 0xFF;
    if (e >= 112 && e <= 140) atomicAdd(&cnt, 1);
    __syncthreads();
    if (threadIdx.x == 0) *flag = (cnt >= 128) ? 1 : 0;
}

// ---------------- degree + CSR build ----------------
__global__ void k_init_cnt(int* __restrict__ cnt, int N) {
    int i = blockIdx.x * blockDim.x + threadIdx.x;
    if (i < N) cnt[i] = 0;
}
__global__ void k_count(const int* __restrict__ cols, int* __restrict__ cnt, int E) {
    int e = blockIdx.x * blockDim.x + threadIdx.x;
    if (e < E) atomicAdd(&cnt[cols[e]], 1);
}
__global__ void k_dis(const int* __restrict__ cnt, float* __restrict__ dis, int N) {
    int i = blockIdx.x * blockDim.x + threadIdx.x;
    if (i < N) dis[i] = rsqrtf(1.0f + (float)cnt[i]);
}
__global__ void k_scan1(const int* __restrict__ cnt, int* __restrict__ rowptr,
                        int* __restrict__ bsum, int N) {
    __shared__ int s[256];
    int t = threadIdx.x;
    int i = blockIdx.x * 256 + t;
    s[t] = (i < N) ? cnt[i] : 0;
    __syncthreads();
    for (int off = 1; off < 256; off <<= 1) {
        int x = (t >= off) ? s[t - off] : 0;
        __syncthreads();
        s[t] += x;
        __syncthreads();
    }
    if (i < N) rowptr[i + 1] = s[t];
    if (t == 255) bsum[blockIdx.x] = s[255];
}
__global__ void k_scan2(int* __restrict__ bsum, int nb) {
    __shared__ int s[256];
    int t = threadIdx.x;
    s[t] = (t < nb) ? bsum[t] : 0;
    __syncthreads();
    for (int off = 1; off < 256; off <<= 1) {
        int x = (t >= off) ? s[t - off] : 0;
        __syncthreads();
        s[t] += x;
        __syncthreads();
    }
    if (t < nb) bsum[t] = s[t];
}
__global__ void k_scan3(int* __restrict__ rowptr, const int* __restrict__ bsum, int N) {
    int i = blockIdx.x * 256 + threadIdx.x;
    if (i == 0) rowptr[0] = 0;
    if (i < N && blockIdx.x > 0) rowptr[i + 1] += bsum[blockIdx.x - 1];
}
__global__ void k_cursor(const int* __restrict__ rowptr, int* __restrict__ cursor, int N) {
    int i = blockIdx.x * 256 + threadIdx.x;
    if (i < N) cursor[i] = rowptr[i];
}
__global__ void k_fill(const int* __restrict__ rows, const int* __restrict__ cols,
                       int* __restrict__ cursor, int* __restrict__ csr, int E) {
    int e = blockIdx.x * blockDim.x + threadIdx.x;
    if (e < E) {
        int c = cols[e], r = rows[e];
        int pos = atomicAdd(&cursor[c], 1);
        csr[pos] = r;
    }
}

__global__ void k_zero_stats(float* __restrict__ stats) {
    int t = threadIdx.x;
    if (t < 16) stats[t] = 0.0f;
}

// ------- conv weight fold+transpose: wt[l][n][k(512)] = c1*W{1,2}[k][n] + (k==n)*c0 -------
__global__ void k_transw2(const void* __restrict__ w1, const void* __restrict__ w2,
                          const int* __restrict__ flag, short* __restrict__ wt) {
    __shared__ float tile[32][33];
    int z = blockIdx.z;
    int lay = z >> 1, m = z & 1;
    const void* src = m ? w2 : w1;
    size_t sbase = (size_t)lay * 65536;
    short* dst = wt + (size_t)lay * 131072 + (size_t)m * 256;  // row stride 512
    float bl = logf(1.0f / (float)(lay + 1) + 1.0f);
    float c0 = 0.5f * (1.0f - bl);
    float c1 = 0.5f * bl;
    int isbf = *flag;
    int tx = threadIdx.x, ty = threadIdx.y;     // (32,8)
    int n0 = blockIdx.x * 32, k0 = blockIdx.y * 32;
    #pragma unroll
    for (int i = 0; i < 4; i++) {
        int k = k0 + ty + i * 8;
        tile[ty + i * 8][tx] = ldf(src, sbase + (size_t)k * 256 + n0 + tx, isbf);
    }
    __syncthreads();
    #pragma unroll
    for (int i = 0; i < 4; i++) {
        int n = n0 + ty + i * 8;
        int k = k0 + tx;
        float v = c1 * tile[tx][ty + i * 8];
        if (k == n) v += c0;
        dst[(size_t)n * 512 + k] = f2s(v);
    }
}

// ------- generic transpose to bf16: dst[n][K] = src[k][n], src is [K, Nc] -------
__global__ void k_transw_lin(const void* __restrict__ src, const int* __restrict__ flag,
                             short* __restrict__ dst, int K, int Nc) {
    __shared__ float tile[32][33];
    int isbf = *flag;
    int tx = threadIdx.x, ty = threadIdx.y;     // (32,8)
    int n0 = blockIdx.x * 32, k0 = blockIdx.y * 32;
    #pragma unroll
    for (int i = 0; i < 4; i++) {
        int k = k0 + ty + i * 8;
        tile[ty + i * 8][tx] = ldf(src, (size_t)k * Nc + n0 + tx, isbf);
    }
    __syncthreads();
    #pragma unroll
    for (int i = 0; i < 4; i++) {
        int n = n0 + ty + i * 8;
        dst[(size_t)n * K + k0 + tx] = f2s(tile[tx][ty + i * 8]);
    }
}

// ------- x conversion to guaranteed-bf16 -------
__global__ void k_convx(const void* __restrict__ x, const int* __restrict__ flag,
                        short* __restrict__ xb, int total) {
    int i = blockIdx.x * 256 + threadIdx.x;
    if (i < total) xb[i] = f2s(ldf(x, i, *flag));
}

// ---- generic MFMA GEMM: out = relu(A @ wt^T + bias). A [M,KK] bf16, wt [BN,KK] bf16 ----
// 512 threads = 8 waves, 16 rows/wave, fragment-major LDS (conflict-free).
// Optional additional sliced output: outs[s][row][32], s = col>>5 (for XCD-sliced gather).
template<int BN, int KK, int FINAL>
__global__ __launch_bounds__(512, 4) void gemm_mfma(
    const short* __restrict__ A, const short* __restrict__ wt,
    const void* __restrict__ bias, const int* __restrict__ flag,
    void* __restrict__ outp, short* __restrict__ outs, int Nn)
{
    constexpr int NT = BN / 16;
    constexpr int BROUNDS = BN / 128;   // 256->2, 128->1
    __shared__ __align__(16) short Atile[128 * 32];
    __shared__ __align__(16) short Btile[BN * 32];
    int t = threadIdx.x;
    int w = t >> 6, lane = t & 63;
    int lr = lane & 15, quad = lane >> 4;
    int row0 = blockIdx.x * 128;
    int sf = t >> 6;           // fragment 0..7
    int srow = lane & 15;      // row within fragment
    int skq = lane >> 4;       // k-quad (8 bf16 = 16B)
    f32x4 acc[NT];
    #pragma unroll
    for (int nt = 0; nt < NT; nt++)
        #pragma unroll
        for (int j = 0; j < 4; j++) acc[nt][j] = 0.f;

    for (int kb = 0; kb < KK; kb += 32) {
        int gr = row0 + sf * 16 + srow;
        if (gr >= Nn) gr = Nn - 1;
        gl_lds16(A + (size_t)gr * KK + kb + skq * 8, Atile + (size_t)t * 8);
        #pragma unroll
        for (int r = 0; r < BROUNDS; r++) {
            int n = (sf + r * 8) * 16 + srow;
            gl_lds16(wt + (size_t)n * KK + kb + skq * 8,
                     Btile + (size_t)(t + r * 512) * 8);
        }
        __syncthreads();
        short8 a = *(const short8*)(Atile + w * 512 + lane * 8);
        #pragma unroll
        for (int nt = 0; nt < NT; nt++) {
            short8 bv = *(const short8*)(Btile + nt * 512 + lane * 8);
            acc[nt] = __builtin_amdgcn_mfma_f32_16x16x32_bf16(a, bv, acc[nt], 0, 0, 0);
        }
        __syncthreads();
    }
    const int isbf = *flag;
    #pragma unroll
    for (int nt = 0; nt < NT; nt++) {
        int gc = nt * 16 + lr;
        float bb = ldf(bias, gc, isbf);
        #pragma unroll
        for (int i = 0; i < 4; i++) {
            int gr = row0 + w * 16 + quad * 4 + i;
            if (gr < Nn) {
                float v = acc[nt][i] + bb;
                v = v > 0.f ? v : 0.f;
                size_t off = (size_t)gr * BN + gc;
                if (FINAL) {
                    if (isbf) ((bf16*)outp)[off] = __float2bfloat16(v);
                    else      ((float*)outp)[off] = v;
                } else {
                    ((bf16*)outp)[off] = __float2bfloat16(v);
                    if (outs) {
                        outs[((size_t)(gc >> 5) * (size_t)Nn + gr) * 32 + (gc & 31)] = f2s(v);
                    }
                }
            }
        }
    }
}

// -------- XCD-sliced CSR gather, 1 node-slice per wave.
// Slice s = blockIdx&7 (block->XCD round-robin): each XCD reads only
// h[:, s*32..s*32+32) = 3.2MB (L2-resident). hsrc layout: [8][N][32] bf16.
// Wave: 8 edge-groups x 8 lanes x 4 cols; software-pipelined csr->(dis,hv) loads.
__global__ __launch_bounds__(256) void k_gather3(
    const int* __restrict__ rowptr, const int* __restrict__ csr,
    const float* __restrict__ dis, const short* __restrict__ hsrc,
    bf16* __restrict__ agg,
    const void* __restrict__ g, const void* __restrict__ b, size_t loff,
    const float* __restrict__ stats2, float invTotal, int useLN,
    const int* __restrict__ flag, int N)
{
    int s = blockIdx.x & 7;
    int chunk = blockIdx.x >> 3;
    int t = threadIdx.x;
    int w = t >> 6, lane = t & 63;
    int node = chunk * 4 + w;
    if (node >= N) return;
    int grp = lane >> 3;           // edge group 0..7
    int cl = (lane & 7) * 4;       // 4 cols per lane within slice
    int col = s * 32 + cl;
    float cA[4], cB[4];
    if (useLN) {
        int isbf = *flag;
        float mu = stats2[0] * invTotal;
        float var = stats2[1] * invTotal - mu * mu;
        var = var > 0.f ? var : 0.f;
        float inv = 1.0f / (sqrtf(var) + EPSLN);
        #pragma unroll
        for (int j = 0; j < 4; j++) {
            float gg = ldf(g, loff + col + j, isbf);
            float bb = ldf(b, loff + col + j, isbf);
            cA[j] = gg * inv;
            cB[j] = fmaf(-gg * inv, mu, bb);
        }
    } else {
        #pragma unroll
        for (int j = 0; j < 4; j++) { cA[j] = 1.0f; cB[j] = 0.0f; }
    }
    const short* hs = hsrc + (size_t)s * (size_t)N * 32;
    float dc = dis[node];
    float a[4] = {0.f, 0.f, 0.f, 0.f};
    if (grp == 0) {
        short4v hv = *(const short4v*)(hs + (size_t)node * 32 + cl);
        #pragma unroll
        for (int j = 0; j < 4; j++) {
            float v = fmaf(cA[j], s2f(hv[j]), cB[j]);
            v = v > 0.f ? v : 0.f;
            a[j] = dc * v;
        }
    }
    int ie = rowptr[node + 1];
    int i = rowptr[node] + grp;
    if (i < ie) {
        int r = __builtin_nontemporal_load(csr + i);
        float wr = dis[r];
        short4v hv = *(const short4v*)(hs + (size_t)r * 32 + cl);
        for (i += 8; i < ie; i += 8) {
            int r2 = __builtin_nontemporal_load(csr + i);
            float wr2 = dis[r2];
            short4v hv2 = *(const short4v*)(hs + (size_t)r2 * 32 + cl);
            #pragma unroll
            for (int j = 0; j < 4; j++) {
                float v = fmaf(cA[j], s2f(hv[j]), cB[j]);
                v = v > 0.f ? v : 0.f;
                a[j] = fmaf(wr, v, a[j]);
            }
            wr = wr2; hv = hv2;
        }
        #pragma unroll
        for (int j = 0; j < 4; j++) {
            float v = fmaf(cA[j], s2f(hv[j]), cB[j]);
            v = v > 0.f ? v : 0.f;
            a[j] = fmaf(wr, v, a[j]);
        }
    }
    #pragma unroll
    for (int j = 0; j < 4; j++) {
        a[j] += __shfl_xor(a[j], 8);
        a[j] += __shfl_xor(a[j], 16);
        a[j] += __shfl_xor(a[j], 32);
    }
    if (grp == 0) {
        short4v o;
        #pragma unroll
        for (int j = 0; j < 4; j++) o[j] = f2s(dc * a[j]);
        *(short4v*)((short*)agg + (size_t)node * DH + col) = o;
    }
}

// ---- layer GEMM (MFMA, fragment-major LDS): h = [agg|x0] @ W' + LN sums ----
// sliced=1: write h in [8][N][32] sliced layout (consumed by k_gather3 only);
// sliced=0 (last layer): row-major (consumed by k_applyT + lin2).
__global__ __launch_bounds__(512, 4) void gemm_layer3(
    const bf16* __restrict__ agg, const bf16* __restrict__ x0,
    const short* __restrict__ wt, bf16* __restrict__ h,
    float* __restrict__ stats2, int sliced, int Nn)
{
    __shared__ __align__(16) short Atile[128 * 32];
    __shared__ __align__(16) short Btile[256 * 32];
    __shared__ float sred[16];
    int t = threadIdx.x;
    int w = t >> 6, lane = t & 63;
    int lr = lane & 15, quad = lane >> 4;
    int row0 = blockIdx.x * 128;
    int sf = t >> 6;
    int srow = lane & 15;
    int skq = lane >> 4;
    f32x4 acc[16];
    #pragma unroll
    for (int nt = 0; nt < 16; nt++)
        #pragma unroll
        for (int j = 0; j < 4; j++) acc[nt][j] = 0.f;

    for (int kb = 0; kb < 512; kb += 32) {
        const short* Asrc = (const short*)((kb < DH) ? agg : x0);
        int ka = (kb & (DH - 1)) + skq * 8;
        int gr = row0 + sf * 16 + srow;
        if (gr >= Nn) gr = Nn - 1;
        gl_lds16(Asrc + (size_t)gr * DH + ka, Atile + (size_t)t * 8);
        #pragma unroll
        for (int r = 0; r < 2; r++) {
            int n = (sf + r * 8) * 16 + srow;
            gl_lds16(wt + (size_t)n * 512 + kb + skq * 8,
                     Btile + (size_t)(t + r * 512) * 8);
        }
        __syncthreads();
        short8 a = *(const short8*)(Atile + w * 512 + lane * 8);
        #pragma unroll
        for (int nt = 0; nt < 16; nt++) {
            short8 bv = *(const short8*)(Btile + nt * 512 + lane * 8);
            acc[nt] = __builtin_amdgcn_mfma_f32_16x16x32_bf16(a, bv, acc[nt], 0, 0, 0);
        }
        __syncthreads();
    }
    short* hS = (short*)h;
    float lsum = 0.f, lsq = 0.f;
    #pragma unroll
    for (int nt = 0; nt < 16; nt++) {
        int gc = nt * 16 + lr;
        #pragma unroll
        for (int i = 0; i < 4; i++) {
            int gr = row0 + w * 16 + quad * 4 + i;
            if (gr < Nn) {
                float v = acc[nt][i];
                if (sliced) {
                    hS[((size_t)(gc >> 5) * (size_t)Nn + gr) * 32 + (gc & 31)] = f2s(v);
                } else {
                    h[(size_t)gr * DH + gc] = __float2bfloat16(v);
                }
                lsum += v;
                lsq += v * v;
            }
        }
    }
    #pragma unroll
    for (int off = 32; off > 0; off >>= 1) {
        lsum += __shfl_down(lsum, off);
        lsq  += __shfl_down(lsq, off);
    }
    if (lane == 0) { sred[w] = lsum; sred[8 + w] = lsq; }
    __syncthreads();
    if (t == 0) {
        float s0 = 0.f, s1 = 0.f;
        #pragma unroll
        for (int i = 0; i < 8; i++) { s0 += sred[i]; s1 += sred[8 + i]; }
        atomicAdd(&stats2[0], s0);
        atomicAdd(&stats2[1], s1);
    }
}

// ------- final LN+relu applied in place to h (layer-8 stats) -------
__global__ void k_applyT(
    bf16* __restrict__ h, const float* __restrict__ stats2, float invTotal,
    const void* __restrict__ g, const void* __restrict__ b, size_t loff,
    const int* __restrict__ flag, int total)
{
    int idx = blockIdx.x * 256 + threadIdx.x;
    if (idx >= total) return;
    const int isbf = *flag;
    float mu = stats2[0] * invTotal;
    float var = stats2[1] * invTotal - mu * mu;
    var = var > 0.f ? var : 0.f;
    float inv = 1.0f / (sqrtf(var) + EPSLN);
    int j = idx & (DH - 1);
    float gg = ldf(g, loff + j, isbf);
    float bb = ldf(b, loff + j, isbf);
    float v = fmaf(gg * inv, __bfloat162float(h[idx]), fmaf(-gg * inv, mu, bb));
    v = v > 0.f ? v : 0.f;
    h[idx] = __float2bfloat16(v);
}

extern "C" void kernel_launch(void* const* d_in, const int* in_sizes, int n_in,
                              void* d_out, int out_size, void* d_ws, size_t ws_size,
                              hipStream_t stream) {
    const void* x      = d_in[0];
    const int*  ei     = (const int*)d_in[1];
    const void* lin1_w = d_in[2];
    const void* lin1_b = d_in[3];
    const void* conv_w1= d_in[4];
    const void* conv_w2= d_in[5];
    const void* gam    = d_in[6];
    const void* bet    = d_in[7];
    const void* lin2_w = d_in[8];
    const void* lin2_b = d_in[9];

    const int N = in_sizes[0] / DIN;
    const int E = in_sizes[1] / 2;
    const int* rows = ei;
    const int* cols = ei + E;
    const size_t NDH = (size_t)N * DH;
    const size_t Nr = ((size_t)N + 255) / 256 * 256;

    char* p = (char*)d_ws;
    auto alloc = [&](size_t bytes) { char* q = p; p += (bytes + 255) & ~(size_t)255; return q; };
    float* dis    = (float*)alloc(Nr * 4);
    float* stats  = (float*)alloc(1024);          // 16 slots: 2 per layer
    int*   flag   = (int*)(stats + 16);
    int*   cnt    = (int*)alloc(Nr * 4);
    int*   rowptr = (int*)alloc((Nr + 256) * 4);
    int*   cursor = (int*)alloc(Nr * 4);
    int*   bsum   = (int*)alloc(1024);
    int*   csr    = (int*)alloc((size_t)E * 4);
    short* wt     = (short*)alloc((size_t)NLAYERS * 131072 * 2);  // 2 MB folded conv weights
    short* w1t    = (short*)alloc((size_t)DH * DIN * 2);          // lin1^T
    short* w2t    = (short*)alloc((size_t)DOUT * DH * 2);         // lin2^T
    short* xb     = (short*)alloc((size_t)N * DIN * 2);           // x as bf16
    bf16*  agg    = (bf16*)alloc(NDH * 2);
    bf16*  x0     = (bf16*)alloc(NDH * 2);
    short* x0s    = (short*)alloc(NDH * 2);       // x0 in sliced [8][N][32] layout
    bf16*  h      = (bf16*)alloc(NDH * 2);        // sliced for layers 0..6, row-major layer 7

    dim3 blk(256);
    int nbN = (N + 255) / 256;
    dim3 gN(nbN);
    dim3 gE((E + 255) / 256);
    dim3 gB((N + 127) / 128);
    dim3 gG((unsigned)(8 * ((N + 3) / 4)));
    dim3 gElem((unsigned)((NDH + 255) / 256));
    dim3 gTW(8, 8, 16);
    dim3 bTW(32, 8);
    dim3 blk512(512);

    k_detect<<<1, 256, 0, stream>>>((const unsigned int*)x, flag);
    k_init_cnt<<<gN, blk, 0, stream>>>(cnt, N);
    k_count<<<gE, blk, 0, stream>>>(cols, cnt, E);
    k_dis<<<gN, blk, 0, stream>>>(cnt, dis, N);
    k_scan1<<<gN, blk, 0, stream>>>(cnt, rowptr, bsum, N);
    k_scan2<<<1, 256, 0, stream>>>(bsum, nbN);
    k_scan3<<<gN, blk, 0, stream>>>(rowptr, bsum, N);
    k_cursor<<<gN, blk, 0, stream>>>(rowptr, cursor, N);
    k_fill<<<gE, blk, 0, stream>>>(rows, cols, cursor, csr, E);
    k_zero_stats<<<1, 64, 0, stream>>>(stats);
    k_transw2<<<gTW, bTW, 0, stream>>>(conv_w1, conv_w2, flag, wt);
    k_transw_lin<<<dim3(DH / 32, DIN / 32), bTW, 0, stream>>>(lin1_w, flag, w1t, DIN, DH);
    k_transw_lin<<<dim3(DOUT / 32, DH / 32), bTW, 0, stream>>>(lin2_w, flag, w2t, DH, DOUT);
    k_convx<<<dim3((unsigned)(((size_t)N * DIN + 255) / 256)), blk, 0, stream>>>(x, flag, xb, N * DIN);

    // lin1: x0 = relu(x @ lin1_w + b); also emit sliced copy for layer-0 gather
    gemm_mfma<DH, DIN, 0><<<gB, blk512, 0, stream>>>(xb, w1t, lin1_b, flag, x0, x0s, N);

    const float invTotal = 1.0f / ((float)N * (float)DH);
    for (int l = 0; l < NLAYERS; l++) {
        const short* hsrc = (l == 0) ? x0s : (const short*)h;
        size_t loff = (l == 0) ? 0 : (size_t)(l - 1) * DH;
        const float* st = (l == 0) ? stats : stats + 2 * (l - 1);
        k_gather3<<<gG, blk, 0, stream>>>(rowptr, csr, dis, hsrc, agg,
                                          gam, bet, loff, st, invTotal,
                                          l > 0 ? 1 : 0, flag, N);
        gemm_layer3<<<gB, blk512, 0, stream>>>(agg, x0, wt + (size_t)l * 131072,
                                               h, stats + 2 * l,
                                               (l < NLAYERS - 1) ? 1 : 0, N);
    }
    // final LN + relu in place (row-major h), then lin2
    k_applyT<<<gElem, blk, 0, stream>>>(h, stats + 2 * (NLAYERS - 1), invTotal,
                                        gam, bet, (size_t)(NLAYERS - 1) * DH,
                                        flag, (int)NDH);
    gemm_mfma<DOUT, DH, 1><<<gB, blk512, 0, stream>>>((const short*)h, w2t, lin2_b,
                                                      flag, d_out, nullptr, N);
}

// Round 8
// 1162.176 us; speedup vs baseline: 1.9169x; 1.9169x over previous
//
#include <hip/hip_runtime.h>
#include <hip/hip_bf16.h>
#include <math.h>

#define DIN 128
#define DH 256
#define DOUT 128
#define NLAYERS 8
#define EPSLN 1e-5f

typedef __hip_bfloat16 bf16;
typedef __attribute__((ext_vector_type(8))) short short8;
typedef __attribute__((ext_vector_type(4))) short short4v;
typedef __attribute__((ext_vector_type(4))) float f32x4;
typedef __attribute__((ext_vector_type(2))) int int2v;

__device__ __forceinline__ float ldf(const void* p, size_t idx, int isbf) {
    if (isbf) return __bfloat162float(((const bf16*)p)[idx]);
    return ((const float*)p)[idx];
}
__device__ __forceinline__ short f2s(float v) {
    bf16 b = __float2bfloat16(v);
    return *reinterpret_cast<short*>(&b);
}
__device__ __forceinline__ float s2f(short s) {
    unsigned int u = ((unsigned int)(unsigned short)s) << 16;
    float f;
    __builtin_memcpy(&f, &u, 4);
    return f;
}
__device__ __forceinline__ void gl_lds16(const void* g, void* l) {
    __builtin_amdgcn_global_load_lds(
        (const __attribute__((address_space(1))) unsigned int*)g,
        (__attribute__((address_space(3))) unsigned int*)l,
        16, 0, 0);
}

// ---------------- dtype probe ----------------
__global__ void k_detect(const unsigned int* __restrict__ xw, int* __restrict__ flag) {
    __shared__ int cnt;
    if (threadIdx.x == 0) cnt = 0;
    __syncthreads();
    unsigned int w = xw[threadIdx.x];
    int e = (w >> 7) & 0xFF;
    if (e >= 112 && e <= 140) atomicAdd(&cnt, 1);
    __syncthreads();
    if (threadIdx.x == 0) *flag = (cnt >= 128) ? 1 : 0;
}

// ---------------- degree + CSR build ----------------
__global__ void k_init_cnt(int* __restrict__ cnt, int N) {
    int i = blockIdx.x * blockDim.x + threadIdx.x;
    if (i < N) cnt[i] = 0;
}
__global__ void k_count(const int* __restrict__ cols, int* __restrict__ cnt, int E) {
    int e = blockIdx.x * blockDim.x + threadIdx.x;
    if (e < E) atomicAdd(&cnt[cols[e]], 1);
}
__global__ void k_dis(const int* __restrict__ cnt, float* __restrict__ dis, int N) {
    int i = blockIdx.x * blockDim.x + threadIdx.x;
    if (i < N) dis[i] = rsqrtf(1.0f + (float)cnt[i]);
}
__global__ void k_scan1(const int* __restrict__ cnt, int* __restrict__ rowptr,
                        int* __restrict__ bsum, int N) {
    __shared__ int s[256];
    int t = threadIdx.x;
    int i = blockIdx.x * 256 + t;
    s[t] = (i < N) ? cnt[i] : 0;
    __syncthreads();
    for (int off = 1; off < 256; off <<= 1) {
        int x = (t >= off) ? s[t - off] : 0;
        __syncthreads();
        s[t] += x;
        __syncthreads();
    }
    if (i < N) rowptr[i + 1] = s[t];
    if (t == 255) bsum[blockIdx.x] = s[255];
}
__global__ void k_scan2(int* __restrict__ bsum, int nb) {
    __shared__ int s[256];
    int t = threadIdx.x;
    s[t] = (t < nb) ? bsum[t] : 0;
    __syncthreads();
    for (int off = 1; off < 256; off <<= 1) {
        int x = (t >= off) ? s[t - off] : 0;
        __syncthreads();
        s[t] += x;
        __syncthreads();
    }
    if (t < nb) bsum[t] = s[t];
}
__global__ void k_scan3(int* __restrict__ rowptr, const int* __restrict__ bsum, int N) {
    int i = blockIdx.x * 256 + threadIdx.x;
    if (i == 0) rowptr[0] = 0;
    if (i < N && blockIdx.x > 0) rowptr[i + 1] += bsum[blockIdx.x - 1];
}
__global__ void k_cursor(const int* __restrict__ rowptr, int* __restrict__ cursor, int N) {
    int i = blockIdx.x * 256 + threadIdx.x;
    if (i < N) cursor[i] = rowptr[i];
}
// fill packed edge records: ew[pos] = {src_row, dis[src_row]} (graph/dis are layer-invariant)
__global__ void k_fill(const int* __restrict__ rows, const int* __restrict__ cols,
                       const float* __restrict__ dis,
                       int* __restrict__ cursor, int2v* __restrict__ ew, int E) {
    int e = blockIdx.x * blockDim.x + threadIdx.x;
    if (e < E) {
        int c = cols[e], r = rows[e];
        int pos = atomicAdd(&cursor[c], 1);
        int2v rec;
        rec.x = r;
        rec.y = __float_as_int(dis[r]);
        ew[pos] = rec;
    }
}

__global__ void k_zero_stats(float* __restrict__ stats) {
    int t = threadIdx.x;
    if (t < 16) stats[t] = 0.0f;
}

// ------- conv weight fold+transpose: wt[l][n][k(512)] = c1*W{1,2}[k][n] + (k==n)*c0 -------
__global__ void k_transw2(const void* __restrict__ w1, const void* __restrict__ w2,
                          const int* __restrict__ flag, short* __restrict__ wt) {
    __shared__ float tile[32][33];
    int z = blockIdx.z;
    int lay = z >> 1, m = z & 1;
    const void* src = m ? w2 : w1;
    size_t sbase = (size_t)lay * 65536;
    short* dst = wt + (size_t)lay * 131072 + (size_t)m * 256;  // row stride 512
    float bl = logf(1.0f / (float)(lay + 1) + 1.0f);
    float c0 = 0.5f * (1.0f - bl);
    float c1 = 0.5f * bl;
    int isbf = *flag;
    int tx = threadIdx.x, ty = threadIdx.y;     // (32,8)
    int n0 = blockIdx.x * 32, k0 = blockIdx.y * 32;
    #pragma unroll
    for (int i = 0; i < 4; i++) {
        int k = k0 + ty + i * 8;
        tile[ty + i * 8][tx] = ldf(src, sbase + (size_t)k * 256 + n0 + tx, isbf);
    }
    __syncthreads();
    #pragma unroll
    for (int i = 0; i < 4; i++) {
        int n = n0 + ty + i * 8;
        int k = k0 + tx;
        float v = c1 * tile[tx][ty + i * 8];
        if (k == n) v += c0;
        dst[(size_t)n * 512 + k] = f2s(v);
    }
}

// ------- generic transpose to bf16: dst[n][K] = src[k][n], src is [K, Nc] -------
__global__ void k_transw_lin(const void* __restrict__ src, const int* __restrict__ flag,
                             short* __restrict__ dst, int K, int Nc) {
    __shared__ float tile[32][33];
    int isbf = *flag;
    int tx = threadIdx.x, ty = threadIdx.y;     // (32,8)
    int n0 = blockIdx.x * 32, k0 = blockIdx.y * 32;
    #pragma unroll
    for (int i = 0; i < 4; i++) {
        int k = k0 + ty + i * 8;
        tile[ty + i * 8][tx] = ldf(src, (size_t)k * Nc + n0 + tx, isbf);
    }
    __syncthreads();
    #pragma unroll
    for (int i = 0; i < 4; i++) {
        int n = n0 + ty + i * 8;
        dst[(size_t)n * K + k0 + tx] = f2s(tile[tx][ty + i * 8]);
    }
}

// ------- x conversion to guaranteed-bf16 -------
__global__ void k_convx(const void* __restrict__ x, const int* __restrict__ flag,
                        short* __restrict__ xb, int total) {
    int i = blockIdx.x * 256 + threadIdx.x;
    if (i < total) xb[i] = f2s(ldf(x, i, *flag));
}

// ---- generic MFMA GEMM: out = relu(A @ wt^T + bias). A [M,KK] bf16, wt [BN,KK] bf16 ----
// 512 threads = 8 waves, 16 rows/wave, fragment-major LDS (conflict-free).
template<int BN, int KK, int FINAL>
__global__ __launch_bounds__(512, 4) void gemm_mfma(
    const short* __restrict__ A, const short* __restrict__ wt,
    const void* __restrict__ bias, const int* __restrict__ flag,
    void* __restrict__ outp, int Nn)
{
    constexpr int NT = BN / 16;
    constexpr int BROUNDS = BN / 128;   // 256->2, 128->1
    __shared__ __align__(16) short Atile[128 * 32];
    __shared__ __align__(16) short Btile[BN * 32];
    int t = threadIdx.x;
    int w = t >> 6, lane = t & 63;
    int lr = lane & 15, quad = lane >> 4;
    int row0 = blockIdx.x * 128;
    int sf = t >> 6;           // fragment 0..7
    int srow = lane & 15;      // row within fragment
    int skq = lane >> 4;       // k-quad (8 bf16 = 16B)
    f32x4 acc[NT];
    #pragma unroll
    for (int nt = 0; nt < NT; nt++)
        #pragma unroll
        for (int j = 0; j < 4; j++) acc[nt][j] = 0.f;

    for (int kb = 0; kb < KK; kb += 32) {
        int gr = row0 + sf * 16 + srow;
        if (gr >= Nn) gr = Nn - 1;
        gl_lds16(A + (size_t)gr * KK + kb + skq * 8, Atile + (size_t)t * 8);
        #pragma unroll
        for (int r = 0; r < BROUNDS; r++) {
            int n = (sf + r * 8) * 16 + srow;
            gl_lds16(wt + (size_t)n * KK + kb + skq * 8,
                     Btile + (size_t)(t + r * 512) * 8);
        }
        __syncthreads();
        short8 a = *(const short8*)(Atile + w * 512 + lane * 8);
        #pragma unroll
        for (int nt = 0; nt < NT; nt++) {
            short8 bv = *(const short8*)(Btile + nt * 512 + lane * 8);
            acc[nt] = __builtin_amdgcn_mfma_f32_16x16x32_bf16(a, bv, acc[nt], 0, 0, 0);
        }
        __syncthreads();
    }
    const int isbf = *flag;
    #pragma unroll
    for (int nt = 0; nt < NT; nt++) {
        int gc = nt * 16 + lr;
        float bb = ldf(bias, gc, isbf);
        #pragma unroll
        for (int i = 0; i < 4; i++) {
            int gr = row0 + w * 16 + quad * 4 + i;
            if (gr < Nn) {
                float v = acc[nt][i] + bb;
                v = v > 0.f ? v : 0.f;
                size_t off = (size_t)gr * BN + gc;
                if (FINAL) {
                    if (isbf) ((bf16*)outp)[off] = __float2bfloat16(v);
                    else      ((float*)outp)[off] = v;
                } else {
                    ((bf16*)outp)[off] = __float2bfloat16(v);
                }
            }
        }
    }
}

// -------- CSR gather, wave-per-node (measured-best shape), packed edge records.
// ew[i] = {r, dis[r]} removes the csr->dis dependent random load per edge.
__global__ __launch_bounds__(256) void k_gather2(
    const int* __restrict__ rowptr, const int2v* __restrict__ ew,
    const float* __restrict__ dis, const bf16* __restrict__ hsrc,
    bf16* __restrict__ agg,
    const void* __restrict__ g, const void* __restrict__ b, size_t loff,
    const float* __restrict__ stats2, float invTotal, int useLN,
    const int* __restrict__ flag, int N)
{
    int gid = blockIdx.x * 256 + threadIdx.x;
    int node = gid >> 6;
    if (node >= N) return;
    int lane = gid & 63;
    int col = lane * 4;
    float cA[4], cB[4];
    if (useLN) {
        int isbf = *flag;
        float mu = stats2[0] * invTotal;
        float var = stats2[1] * invTotal - mu * mu;
        var = var > 0.f ? var : 0.f;
        float inv = 1.0f / (sqrtf(var) + EPSLN);
        #pragma unroll
        for (int j = 0; j < 4; j++) {
            float gg = ldf(g, loff + col + j, isbf);
            float bb = ldf(b, loff + col + j, isbf);
            cA[j] = gg * inv;
            cB[j] = fmaf(-gg * inv, mu, bb);
        }
    } else {
        #pragma unroll
        for (int j = 0; j < 4; j++) { cA[j] = 1.0f; cB[j] = 0.0f; }
    }
    const short* hs = (const short*)hsrc;
    float dc = dis[node];
    float acc[4], acc2[4];
    {
        short4v hv = *(const short4v*)(hs + (size_t)node * DH + col);
        #pragma unroll
        for (int j = 0; j < 4; j++) {
            float v = fmaf(cA[j], s2f(hv[j]), cB[j]);
            v = v > 0.f ? v : 0.f;
            acc[j] = dc * v;
            acc2[j] = 0.f;
        }
    }
    int i = rowptr[node], e1 = rowptr[node + 1];
    for (; i + 4 <= e1; i += 4) {
        int2v e0 = __builtin_nontemporal_load(ew + i);
        int2v e1v = __builtin_nontemporal_load(ew + i + 1);
        int2v e2 = __builtin_nontemporal_load(ew + i + 2);
        int2v e3 = __builtin_nontemporal_load(ew + i + 3);
        float w0 = __int_as_float(e0.y), w1 = __int_as_float(e1v.y);
        float w2 = __int_as_float(e2.y), w3 = __int_as_float(e3.y);
        short4v v0 = *(const short4v*)(hs + (size_t)e0.x * DH + col);
        short4v v1 = *(const short4v*)(hs + (size_t)e1v.x * DH + col);
        short4v v2 = *(const short4v*)(hs + (size_t)e2.x * DH + col);
        short4v v3 = *(const short4v*)(hs + (size_t)e3.x * DH + col);
        #pragma unroll
        for (int j = 0; j < 4; j++) {
            float a0 = fmaf(cA[j], s2f(v0[j]), cB[j]); a0 = a0 > 0.f ? a0 : 0.f;
            float a1 = fmaf(cA[j], s2f(v1[j]), cB[j]); a1 = a1 > 0.f ? a1 : 0.f;
            float a2 = fmaf(cA[j], s2f(v2[j]), cB[j]); a2 = a2 > 0.f ? a2 : 0.f;
            float a3 = fmaf(cA[j], s2f(v3[j]), cB[j]); a3 = a3 > 0.f ? a3 : 0.f;
            acc[j]  = fmaf(w0, a0, acc[j]);
            acc2[j] = fmaf(w1, a1, acc2[j]);
            acc[j]  = fmaf(w2, a2, acc[j]);
            acc2[j] = fmaf(w3, a3, acc2[j]);
        }
    }
    for (; i < e1; i++) {
        int2v e0 = __builtin_nontemporal_load(ew + i);
        float wr = __int_as_float(e0.y);
        short4v v0 = *(const short4v*)(hs + (size_t)e0.x * DH + col);
        #pragma unroll
        for (int j = 0; j < 4; j++) {
            float a0 = fmaf(cA[j], s2f(v0[j]), cB[j]); a0 = a0 > 0.f ? a0 : 0.f;
            acc[j] = fmaf(wr, a0, acc[j]);
        }
    }
    short4v o;
    #pragma unroll
    for (int j = 0; j < 4; j++) o[j] = f2s(dc * (acc[j] + acc2[j]));
    *(short4v*)((short*)agg + (size_t)node * DH + col) = o;
}

// ---- layer GEMM (MFMA, fragment-major LDS): h = [agg|x0] @ W' + LN sums ----
// 512 threads = 8 waves, 16 rows/wave, acc[16] (64 VGPR) -> 2 blocks/CU co-resident.
__global__ __launch_bounds__(512, 4) void gemm_layer3(
    const bf16* __restrict__ agg, const bf16* __restrict__ x0,
    const short* __restrict__ wt, bf16* __restrict__ h,
    float* __restrict__ stats2, int Nn)
{
    __shared__ __align__(16) short Atile[128 * 32];
    __shared__ __align__(16) short Btile[256 * 32];
    __shared__ float sred[16];
    int t = threadIdx.x;
    int w = t >> 6, lane = t & 63;
    int lr = lane & 15, quad = lane >> 4;
    int row0 = blockIdx.x * 128;
    int sf = t >> 6;
    int srow = lane & 15;
    int skq = lane >> 4;
    f32x4 acc[16];
    #pragma unroll
    for (int nt = 0; nt < 16; nt++)
        #pragma unroll
        for (int j = 0; j < 4; j++) acc[nt][j] = 0.f;

    for (int kb = 0; kb < 512; kb += 32) {
        const short* Asrc = (const short*)((kb < DH) ? agg : x0);
        int ka = (kb & (DH - 1)) + skq * 8;
        int gr = row0 + sf * 16 + srow;
        if (gr >= Nn) gr = Nn - 1;
        gl_lds16(Asrc + (size_t)gr * DH + ka, Atile + (size_t)t * 8);
        #pragma unroll
        for (int r = 0; r < 2; r++) {
            int n = (sf + r * 8) * 16 + srow;
            gl_lds16(wt + (size_t)n * 512 + kb + skq * 8,
                     Btile + (size_t)(t + r * 512) * 8);
        }
        __syncthreads();
        short8 a = *(const short8*)(Atile + w * 512 + lane * 8);
        #pragma unroll
        for (int nt = 0; nt < 16; nt++) {
            short8 bv = *(const short8*)(Btile + nt * 512 + lane * 8);
            acc[nt] = __builtin_amdgcn_mfma_f32_16x16x32_bf16(a, bv, acc[nt], 0, 0, 0);
        }
        __syncthreads();
    }
    float lsum = 0.f, lsq = 0.f;
    #pragma unroll
    for (int nt = 0; nt < 16; nt++) {
        int gc = nt * 16 + lr;
        #pragma unroll
        for (int i = 0; i < 4; i++) {
            int gr = row0 + w * 16 + quad * 4 + i;
            if (gr < Nn) {
                float v = acc[nt][i];
                h[(size_t)gr * DH + gc] = __float2bfloat16(v);
                lsum += v;
                lsq += v * v;
            }
        }
    }
    #pragma unroll
    for (int off = 32; off > 0; off >>= 1) {
        lsum += __shfl_down(lsum, off);
        lsq  += __shfl_down(lsq, off);
    }
    if (lane == 0) { sred[w] = lsum; sred[8 + w] = lsq; }
    __syncthreads();
    if (t == 0) {
        float s0 = 0.f, s1 = 0.f;
        #pragma unroll
        for (int i = 0; i < 8; i++) { s0 += sred[i]; s1 += sred[8 + i]; }
        atomicAdd(&stats2[0], s0);
        atomicAdd(&stats2[1], s1);
    }
}

// ------- final LN+relu applied in place to h (layer-8 stats) -------
__global__ void k_applyT(
    bf16* __restrict__ h, const float* __restrict__ stats2, float invTotal,
    const void* __restrict__ g, const void* __restrict__ b, size_t loff,
    const int* __restrict__ flag, int total)
{
    int idx = blockIdx.x * 256 + threadIdx.x;
    if (idx >= total) return;
    const int isbf = *flag;
    float mu = stats2[0] * invTotal;
    float var = stats2[1] * invTotal - mu * mu;
    var = var > 0.f ? var : 0.f;
    float inv = 1.0f / (sqrtf(var) + EPSLN);
    int j = idx & (DH - 1);
    float gg = ldf(g, loff + j, isbf);
    float bb = ldf(b, loff + j, isbf);
    float v = fmaf(gg * inv, __bfloat162float(h[idx]), fmaf(-gg * inv, mu, bb));
    v = v > 0.f ? v : 0.f;
    h[idx] = __float2bfloat16(v);
}

extern "C" void kernel_launch(void* const* d_in, const int* in_sizes, int n_in,
                              void* d_out, int out_size, void* d_ws, size_t ws_size,
                              hipStream_t stream) {
    const void* x      = d_in[0];
    const int*  ei     = (const int*)d_in[1];
    const void* lin1_w = d_in[2];
    const void* lin1_b = d_in[3];
    const void* conv_w1= d_in[4];
    const void* conv_w2= d_in[5];
    const void* gam    = d_in[6];
    const void* bet    = d_in[7];
    const void* lin2_w = d_in[8];
    const void* lin2_b = d_in[9];

    const int N = in_sizes[0] / DIN;
    const int E = in_sizes[1] / 2;
    const int* rows = ei;
    const int* cols = ei + E;
    const size_t NDH = (size_t)N * DH;
    const size_t Nr = ((size_t)N + 255) / 256 * 256;

    char* p = (char*)d_ws;
    auto alloc = [&](size_t bytes) { char* q = p; p += (bytes + 255) & ~(size_t)255; return q; };
    float* dis    = (float*)alloc(Nr * 4);
    float* stats  = (float*)alloc(1024);          // 16 slots: 2 per layer
    int*   flag   = (int*)(stats + 16);
    int*   cnt    = (int*)alloc(Nr * 4);
    int*   rowptr = (int*)alloc((Nr + 256) * 4);
    int*   cursor = (int*)alloc(Nr * 4);
    int*   bsum   = (int*)alloc(1024);
    int2v* ew     = (int2v*)alloc((size_t)E * 8);  // packed {src, dis[src]} edge records
    short* wt     = (short*)alloc((size_t)NLAYERS * 131072 * 2);  // 2 MB folded conv weights
    short* w1t    = (short*)alloc((size_t)DH * DIN * 2);          // lin1^T
    short* w2t    = (short*)alloc((size_t)DOUT * DH * 2);         // lin2^T
    short* xb     = (short*)alloc((size_t)N * DIN * 2);           // x as bf16
    bf16*  agg    = (bf16*)alloc(NDH * 2);
    bf16*  x0     = (bf16*)alloc(NDH * 2);
    bf16*  h      = (bf16*)alloc(NDH * 2);

    dim3 blk(256);
    int nbN = (N + 255) / 256;
    dim3 gN(nbN);
    dim3 gE((E + 255) / 256);
    dim3 gB((N + 127) / 128);
    dim3 gG((N + 3) / 4);
    dim3 gElem((unsigned)((NDH + 255) / 256));
    dim3 gTW(8, 8, 16);
    dim3 bTW(32, 8);
    dim3 blk512(512);

    k_detect<<<1, 256, 0, stream>>>((const unsigned int*)x, flag);
    k_init_cnt<<<gN, blk, 0, stream>>>(cnt, N);
    k_count<<<gE, blk, 0, stream>>>(cols, cnt, E);
    k_dis<<<gN, blk, 0, stream>>>(cnt, dis, N);
    k_scan1<<<gN, blk, 0, stream>>>(cnt, rowptr, bsum, N);
    k_scan2<<<1, 256, 0, stream>>>(bsum, nbN);
    k_scan3<<<gN, blk, 0, stream>>>(rowptr, bsum, N);
    k_cursor<<<gN, blk, 0, stream>>>(rowptr, cursor, N);
    k_fill<<<gE, blk, 0, stream>>>(rows, cols, dis, cursor, ew, E);
    k_zero_stats<<<1, 64, 0, stream>>>(stats);
    k_transw2<<<gTW, bTW, 0, stream>>>(conv_w1, conv_w2, flag, wt);
    k_transw_lin<<<dim3(DH / 32, DIN / 32), bTW, 0, stream>>>(lin1_w, flag, w1t, DIN, DH);
    k_transw_lin<<<dim3(DOUT / 32, DH / 32), bTW, 0, stream>>>(lin2_w, flag, w2t, DH, DOUT);
    k_convx<<<dim3((unsigned)(((size_t)N * DIN + 255) / 256)), blk, 0, stream>>>(x, flag, xb, N * DIN);

    // lin1: x0 = relu(x @ lin1_w + b)
    gemm_mfma<DH, DIN, 0><<<gB, blk512, 0, stream>>>(xb, w1t, lin1_b, flag, x0, N);

    const float invTotal = 1.0f / ((float)N * (float)DH);
    for (int l = 0; l < NLAYERS; l++) {
        const bf16* hsrc = (l == 0) ? x0 : h;
        size_t loff = (l == 0) ? 0 : (size_t)(l - 1) * DH;
        const float* st = (l == 0) ? stats : stats + 2 * (l - 1);
        k_gather2<<<gG, blk, 0, stream>>>(rowptr, ew, dis, hsrc, agg,
                                          gam, bet, loff, st, invTotal,
                                          l > 0 ? 1 : 0, flag, N);
        gemm_layer3<<<gB, blk512, 0, stream>>>(agg, x0, wt + (size_t)l * 131072,
                                               h, stats + 2 * l, N);
    }
    // final LN + relu in place, then lin2
    k_applyT<<<gElem, blk, 0, stream>>>(h, stats + 2 * (NLAYERS - 1), invTotal,
                                        gam, bet, (size_t)(NLAYERS - 1) * DH,
                                        flag, (int)NDH);
    gemm_mfma<DOUT, DH, 1><<<gB, blk512, 0, stream>>>((const short*)h, w2t, lin2_b,
                                                      flag, d_out, N);
}

// Round 18
// 1095.600 us; speedup vs baseline: 2.0334x; 1.0608x over previous
//
#include <hip/hip_runtime.h>
#include <hip/hip_bf16.h>
#include <math.h>

#define DIN 128
#define DH 256
#define DOUT 128
#define NLAYERS 8
#define EPSLN 1e-5f

typedef __hip_bfloat16 bf16;
typedef __attribute__((ext_vector_type(8))) short short8;
typedef __attribute__((ext_vector_type(4))) short short4v;
typedef __attribute__((ext_vector_type(4))) float f32x4;

__device__ __forceinline__ float ldf(const void* p, size_t idx, int isbf) {
    if (isbf) return __bfloat162float(((const bf16*)p)[idx]);
    return ((const float*)p)[idx];
}
__device__ __forceinline__ short f2s(float v) {
    bf16 b = __float2bfloat16(v);
    return *reinterpret_cast<short*>(&b);
}
__device__ __forceinline__ float s2f(short s) {
    unsigned int u = ((unsigned int)(unsigned short)s) << 16;
    float f;
    __builtin_memcpy(&f, &u, 4);
    return f;
}
__device__ __forceinline__ void gl_lds16(const void* g, void* l) {
    __builtin_amdgcn_global_load_lds(
        (const __attribute__((address_space(1))) unsigned int*)g,
        (__attribute__((address_space(3))) unsigned int*)l,
        16, 0, 0);
}

// ---------------- dtype probe ----------------
__global__ void k_detect(const unsigned int* __restrict__ xw, int* __restrict__ flag) {
    __shared__ int cnt;
    if (threadIdx.x == 0) cnt = 0;
    __syncthreads();
    unsigned int w = xw[threadIdx.x];
    int e = (w >> 7) & 0xFF;
    if (e >= 112 && e <= 140) atomicAdd(&cnt, 1);
    __syncthreads();
    if (threadIdx.x == 0) *flag = (cnt >= 128) ? 1 : 0;
}

// ---------------- degree + CSR build ----------------
__global__ void k_init_cnt(int* __restrict__ cnt, int N) {
    int i = blockIdx.x * blockDim.x + threadIdx.x;
    if (i < N) cnt[i] = 0;
}
__global__ void k_count(const int* __restrict__ cols, int* __restrict__ cnt, int E) {
    int e = blockIdx.x * blockDim.x + threadIdx.x;
    if (e < E) atomicAdd(&cnt[cols[e]], 1);
}
__global__ void k_dis(const int* __restrict__ cnt, float* __restrict__ dis, int N) {
    int i = blockIdx.x * blockDim.x + threadIdx.x;
    if (i < N) dis[i] = rsqrtf(1.0f + (float)cnt[i]);
}
__global__ void k_scan1(const int* __restrict__ cnt, int* __restrict__ rowptr,
                        int* __restrict__ bsum, int N) {
    __shared__ int s[256];
    int t = threadIdx.x;
    int i = blockIdx.x * 256 + t;
    s[t] = (i < N) ? cnt[i] : 0;
    __syncthreads();
    for (int off = 1; off < 256; off <<= 1) {
        int x = (t >= off) ? s[t - off] : 0;
        __syncthreads();
        s[t] += x;
        __syncthreads();
    }
    if (i < N) rowptr[i + 1] = s[t];
    if (t == 255) bsum[blockIdx.x] = s[255];
}
__global__ void k_scan2(int* __restrict__ bsum, int nb) {
    __shared__ int s[256];
    int t = threadIdx.x;
    s[t] = (t < nb) ? bsum[t] : 0;
    __syncthreads();
    for (int off = 1; off < 256; off <<= 1) {
        int x = (t >= off) ? s[t - off] : 0;
        __syncthreads();
        s[t] += x;
        __syncthreads();
    }
    if (t < nb) bsum[t] = s[t];
}
__global__ void k_scan3(int* __restrict__ rowptr, const int* __restrict__ bsum, int N) {
    int i = blockIdx.x * 256 + threadIdx.x;
    if (i == 0) rowptr[0] = 0;
    if (i < N && blockIdx.x > 0) rowptr[i + 1] += bsum[blockIdx.x - 1];
}
__global__ void k_cursor(const int* __restrict__ rowptr, int* __restrict__ cursor, int N) {
    int i = blockIdx.x * 256 + threadIdx.x;
    if (i < N) cursor[i] = rowptr[i];
}
__global__ void k_fill(const int* __restrict__ rows, const int* __restrict__ cols,
                       int* __restrict__ cursor, int* __restrict__ csr, int E) {
    int e = blockIdx.x * blockDim.x + threadIdx.x;
    if (e < E) {
        int c = cols[e], r = rows[e];
        int pos = atomicAdd(&cursor[c], 1);
        csr[pos] = r;
    }
}

__global__ void k_zero_stats(float* __restrict__ stats) {
    int t = threadIdx.x;
    if (t < 16) stats[t] = 0.0f;
}

// ------- conv weight fold+transpose: wt[l][n][k(512)] = c1*W{1,2}[k][n] + (k==n)*c0 -------
__global__ void k_transw2(const void* __restrict__ w1, const void* __restrict__ w2,
                          const int* __restrict__ flag, short* __restrict__ wt) {
    __shared__ float tile[32][33];
    int z = blockIdx.z;
    int lay = z >> 1, m = z & 1;
    const void* src = m ? w2 : w1;
    size_t sbase = (size_t)lay * 65536;
    short* dst = wt + (size_t)lay * 131072 + (size_t)m * 256;  // row stride 512
    float bl = logf(1.0f / (float)(lay + 1) + 1.0f);
    float c0 = 0.5f * (1.0f - bl);
    float c1 = 0.5f * bl;
    int isbf = *flag;
    int tx = threadIdx.x, ty = threadIdx.y;     // (32,8)
    int n0 = blockIdx.x * 32, k0 = blockIdx.y * 32;
    #pragma unroll
    for (int i = 0; i < 4; i++) {
        int k = k0 + ty + i * 8;
        tile[ty + i * 8][tx] = ldf(src, sbase + (size_t)k * 256 + n0 + tx, isbf);
    }
    __syncthreads();
    #pragma unroll
    for (int i = 0; i < 4; i++) {
        int n = n0 + ty + i * 8;
        int k = k0 + tx;
        float v = c1 * tile[tx][ty + i * 8];
        if (k == n) v += c0;
        dst[(size_t)n * 512 + k] = f2s(v);
    }
}

// ------- generic transpose to bf16: dst[n][K] = src[k][n], src is [K, Nc] -------
__global__ void k_transw_lin(const void* __restrict__ src, const int* __restrict__ flag,
                             short* __restrict__ dst, int K, int Nc) {
    __shared__ float tile[32][33];
    int isbf = *flag;
    int tx = threadIdx.x, ty = threadIdx.y;     // (32,8)
    int n0 = blockIdx.x * 32, k0 = blockIdx.y * 32;
    #pragma unroll
    for (int i = 0; i < 4; i++) {
        int k = k0 + ty + i * 8;
        tile[ty + i * 8][tx] = ldf(src, (size_t)k * Nc + n0 + tx, isbf);
    }
    __syncthreads();
    #pragma unroll
    for (int i = 0; i < 4; i++) {
        int n = n0 + ty + i * 8;
        dst[(size_t)n * K + k0 + tx] = f2s(tile[tx][ty + i * 8]);
    }
}

// ------- x conversion to guaranteed-bf16 -------
__global__ void k_convx(const void* __restrict__ x, const int* __restrict__ flag,
                        short* __restrict__ xb, int total) {
    int i = blockIdx.x * 256 + threadIdx.x;
    if (i < total) xb[i] = f2s(ldf(x, i, *flag));
}

// ---- generic MFMA GEMM: out = relu(A @ wt^T + bias). A [M,KK] bf16, wt [BN,KK] bf16 ----
// 512 threads = 8 waves, 16 rows/wave, fragment-major LDS (conflict-free).
// T3-minimum 2-phase: double-buffered LDS, STAGE(next) issued before compute(cur),
// single __syncthreads per K-step (compiler barrier drains vmcnt+lgkmcnt).
template<int BN, int KK, int FINAL>
__global__ __launch_bounds__(512, 4) void gemm_mfma(
    const short* __restrict__ A, const short* __restrict__ wt,
    const void* __restrict__ bias, const int* __restrict__ flag,
    void* __restrict__ outp, int Nn)
{
    constexpr int NT = BN / 16;
    constexpr int BROUNDS = BN / 128;   // 256->2, 128->1
    constexpr int NSTEP = KK / 32;
    __shared__ __align__(16) short Atile[2][128 * 32];
    __shared__ __align__(16) short Btile[2][BN * 32];
    int t = threadIdx.x;
    int w = t >> 6, lane = t & 63;
    int lr = lane & 15, quad = lane >> 4;
    int row0 = blockIdx.x * 128;
    int sf = t >> 6;           // fragment 0..7
    int srow = lane & 15;      // row within fragment
    int skq = lane >> 4;       // k-quad (8 bf16 = 16B)
    int gr = row0 + sf * 16 + srow;
    if (gr >= Nn) gr = Nn - 1;
    f32x4 acc[NT];
    #pragma unroll
    for (int nt = 0; nt < NT; nt++)
        #pragma unroll
        for (int j = 0; j < 4; j++) acc[nt][j] = 0.f;

    auto stage = [&](int buf, int kb) {
        gl_lds16(A + (size_t)gr * KK + kb + skq * 8, Atile[buf] + (size_t)t * 8);
        #pragma unroll
        for (int r = 0; r < BROUNDS; r++) {
            int n = (sf + r * 8) * 16 + srow;
            gl_lds16(wt + (size_t)n * KK + kb + skq * 8,
                     Btile[buf] + (size_t)(t + r * 512) * 8);
        }
    };

    stage(0, 0);
    __syncthreads();
    int cur = 0;
    for (int step = 0; step < NSTEP; step++) {
        if (step < NSTEP - 1) stage(cur ^ 1, (step + 1) * 32);
        short8 a = *(const short8*)(Atile[cur] + w * 512 + lane * 8);
        #pragma unroll
        for (int nt = 0; nt < NT; nt++) {
            short8 bv = *(const short8*)(Btile[cur] + nt * 512 + lane * 8);
            acc[nt] = __builtin_amdgcn_mfma_f32_16x16x32_bf16(a, bv, acc[nt], 0, 0, 0);
        }
        __syncthreads();
        cur ^= 1;
    }
    const int isbf = *flag;
    #pragma unroll
    for (int nt = 0; nt < NT; nt++) {
        int gc = nt * 16 + lr;
        float bb = ldf(bias, gc, isbf);
        #pragma unroll
        for (int i = 0; i < 4; i++) {
            int grr = row0 + w * 16 + quad * 4 + i;
            if (grr < Nn) {
                float v = acc[nt][i] + bb;
                v = v > 0.f ? v : 0.f;
                size_t off = (size_t)grr * BN + gc;
                if (FINAL) {
                    if (isbf) ((bf16*)outp)[off] = __float2bfloat16(v);
                    else      ((float*)outp)[off] = v;
                } else {
                    ((bf16*)outp)[off] = __float2bfloat16(v);
                }
            }
        }
    }
}

// -------- CSR gather, wave-per-node (measured-best shape, Round-2 exact). --------
__global__ __launch_bounds__(256) void k_gather2(
    const int* __restrict__ rowptr, const int* __restrict__ csr,
    const float* __restrict__ dis, const bf16* __restrict__ hsrc,
    bf16* __restrict__ agg,
    const void* __restrict__ g, const void* __restrict__ b, size_t loff,
    const float* __restrict__ stats2, float invTotal, int useLN,
    const int* __restrict__ flag, int N)
{
    int gid = blockIdx.x * 256 + threadIdx.x;
    int node = gid >> 6;
    if (node >= N) return;
    int lane = gid & 63;
    int col = lane * 4;
    float cA[4], cB[4];
    if (useLN) {
        int isbf = *flag;
        float mu = stats2[0] * invTotal;
        float var = stats2[1] * invTotal - mu * mu;
        var = var > 0.f ? var : 0.f;
        float inv = 1.0f / (sqrtf(var) + EPSLN);
        #pragma unroll
        for (int j = 0; j < 4; j++) {
            float gg = ldf(g, loff + col + j, isbf);
            float bb = ldf(b, loff + col + j, isbf);
            cA[j] = gg * inv;
            cB[j] = fmaf(-gg * inv, mu, bb);
        }
    } else {
        #pragma unroll
        for (int j = 0; j < 4; j++) { cA[j] = 1.0f; cB[j] = 0.0f; }
    }
    const short* hs = (const short*)hsrc;
    float dc = dis[node];
    float acc[4], acc2[4];
    {
        short4v hv = *(const short4v*)(hs + (size_t)node * DH + col);
        #pragma unroll
        for (int j = 0; j < 4; j++) {
            float v = fmaf(cA[j], s2f(hv[j]), cB[j]);
            v = v > 0.f ? v : 0.f;
            acc[j] = dc * v;
            acc2[j] = 0.f;
        }
    }
    int i = rowptr[node], e1 = rowptr[node + 1];
    for (; i + 4 <= e1; i += 4) {
        int r0 = csr[i], r1 = csr[i + 1], r2 = csr[i + 2], r3 = csr[i + 3];
        float w0 = dis[r0], w1 = dis[r1], w2 = dis[r2], w3 = dis[r3];
        short4v v0 = *(const short4v*)(hs + (size_t)r0 * DH + col);
        short4v v1 = *(const short4v*)(hs + (size_t)r1 * DH + col);
        short4v v2 = *(const short4v*)(hs + (size_t)r2 * DH + col);
        short4v v3 = *(const short4v*)(hs + (size_t)r3 * DH + col);
        #pragma unroll
        for (int j = 0; j < 4; j++) {
            float a0 = fmaf(cA[j], s2f(v0[j]), cB[j]); a0 = a0 > 0.f ? a0 : 0.f;
            float a1 = fmaf(cA[j], s2f(v1[j]), cB[j]); a1 = a1 > 0.f ? a1 : 0.f;
            float a2 = fmaf(cA[j], s2f(v2[j]), cB[j]); a2 = a2 > 0.f ? a2 : 0.f;
            float a3 = fmaf(cA[j], s2f(v3[j]), cB[j]); a3 = a3 > 0.f ? a3 : 0.f;
            acc[j]  = fmaf(w0, a0, acc[j]);
            acc2[j] = fmaf(w1, a1, acc2[j]);
            acc[j]  = fmaf(w2, a2, acc[j]);
            acc2[j] = fmaf(w3, a3, acc2[j]);
        }
    }
    for (; i < e1; i++) {
        int r = csr[i];
        float wr = dis[r];
        short4v v0 = *(const short4v*)(hs + (size_t)r * DH + col);
        #pragma unroll
        for (int j = 0; j < 4; j++) {
            float a0 = fmaf(cA[j], s2f(v0[j]), cB[j]); a0 = a0 > 0.f ? a0 : 0.f;
            acc[j] = fmaf(wr, a0, acc[j]);
        }
    }
    short4v o;
    #pragma unroll
    for (int j = 0; j < 4; j++) o[j] = f2s(dc * (acc[j] + acc2[j]));
    *(short4v*)((short*)agg + (size_t)node * DH + col) = o;
}

// ---- layer GEMM (MFMA, fragment-major LDS, 2-phase dbuf): h = [agg|x0] @ W' + LN sums ----
__global__ __launch_bounds__(512, 4) void gemm_layer3(
    const bf16* __restrict__ agg, const bf16* __restrict__ x0,
    const short* __restrict__ wt, bf16* __restrict__ h,
    float* __restrict__ stats2, int Nn)
{
    __shared__ __align__(16) short Atile[2][128 * 32];
    __shared__ __align__(16) short Btile[2][256 * 32];
    __shared__ float sred[16];
    int t = threadIdx.x;
    int w = t >> 6, lane = t & 63;
    int lr = lane & 15, quad = lane >> 4;
    int row0 = blockIdx.x * 128;
    int sf = t >> 6;
    int srow = lane & 15;
    int skq = lane >> 4;
    int gr = row0 + sf * 16 + srow;
    if (gr >= Nn) gr = Nn - 1;
    f32x4 acc[16];
    #pragma unroll
    for (int nt = 0; nt < 16; nt++)
        #pragma unroll
        for (int j = 0; j < 4; j++) acc[nt][j] = 0.f;

    auto stage = [&](int buf, int kb) {
        const short* Asrc = (const short*)((kb < DH) ? agg : x0);
        int ka = (kb & (DH - 1)) + skq * 8;
        gl_lds16(Asrc + (size_t)gr * DH + ka, Atile[buf] + (size_t)t * 8);
        #pragma unroll
        for (int r = 0; r < 2; r++) {
            int n = (sf + r * 8) * 16 + srow;
            gl_lds16(wt + (size_t)n * 512 + kb + skq * 8,
                     Btile[buf] + (size_t)(t + r * 512) * 8);
        }
    };

    stage(0, 0);
    __syncthreads();
    int cur = 0;
    for (int step = 0; step < 16; step++) {
        if (step < 15) stage(cur ^ 1, (step + 1) * 32);
        short8 a = *(const short8*)(Atile[cur] + w * 512 + lane * 8);
        #pragma unroll
        for (int nt = 0; nt < 16; nt++) {
            short8 bv = *(const short8*)(Btile[cur] + nt * 512 + lane * 8);
            acc[nt] = __builtin_amdgcn_mfma_f32_16x16x32_bf16(a, bv, acc[nt], 0, 0, 0);
        }
        __syncthreads();
        cur ^= 1;
    }
    float lsum = 0.f, lsq = 0.f;
    #pragma unroll
    for (int nt = 0; nt < 16; nt++) {
        int gc = nt * 16 + lr;
        #pragma unroll
        for (int i = 0; i < 4; i++) {
            int grr = row0 + w * 16 + quad * 4 + i;
            if (grr < Nn) {
                float v = acc[nt][i];
                h[(size_t)grr * DH + gc] = __float2bfloat16(v);
                lsum += v;
                lsq += v * v;
            }
        }
    }
    #pragma unroll
    for (int off = 32; off > 0; off >>= 1) {
        lsum += __shfl_down(lsum, off);
        lsq  += __shfl_down(lsq, off);
    }
    if (lane == 0) { sred[w] = lsum; sred[8 + w] = lsq; }
    __syncthreads();
    if (t == 0) {
        float s0 = 0.f, s1 = 0.f;
        #pragma unroll
        for (int i = 0; i < 8; i++) { s0 += sred[i]; s1 += sred[8 + i]; }
        atomicAdd(&stats2[0], s0);
        atomicAdd(&stats2[1], s1);
    }
}

// ------- final LN+relu applied in place to h (layer-8 stats) -------
__global__ void k_applyT(
    bf16* __restrict__ h, const float* __restrict__ stats2, float invTotal,
    const void* __restrict__ g, const void* __restrict__ b, size_t loff,
    const int* __restrict__ flag, int total)
{
    int idx = blockIdx.x * 256 + threadIdx.x;
    if (idx >= total) return;
    const int isbf = *flag;
    float mu = stats2[0] * invTotal;
    float var = stats2[1] * invTotal - mu * mu;
    var = var > 0.f ? var : 0.f;
    float inv = 1.0f / (sqrtf(var) + EPSLN);
    int j = idx & (DH - 1);
    float gg = ldf(g, loff + j, isbf);
    float bb = ldf(b, loff + j, isbf);
    float v = fmaf(gg * inv, __bfloat162float(h[idx]), fmaf(-gg * inv, mu, bb));
    v = v > 0.f ? v : 0.f;
    h[idx] = __float2bfloat16(v);
}

extern "C" void kernel_launch(void* const* d_in, const int* in_sizes, int n_in,
                              void* d_out, int out_size, void* d_ws, size_t ws_size,
                              hipStream_t stream) {
    const void* x      = d_in[0];
    const int*  ei     = (const int*)d_in[1];
    const void* lin1_w = d_in[2];
    const void* lin1_b = d_in[3];
    const void* conv_w1= d_in[4];
    const void* conv_w2= d_in[5];
    const void* gam    = d_in[6];
    const void* bet    = d_in[7];
    const void* lin2_w = d_in[8];
    const void* lin2_b = d_in[9];

    const int N = in_sizes[0] / DIN;
    const int E = in_sizes[1] / 2;
    const int* rows = ei;
    const int* cols = ei + E;
    const size_t NDH = (size_t)N * DH;
    const size_t Nr = ((size_t)N + 255) / 256 * 256;

    char* p = (char*)d_ws;
    auto alloc = [&](size_t bytes) { char* q = p; p += (bytes + 255) & ~(size_t)255; return q; };
    float* dis    = (float*)alloc(Nr * 4);
    float* stats  = (float*)alloc(1024);          // 16 slots: 2 per layer
    int*   flag   = (int*)(stats + 16);
    int*   cnt    = (int*)alloc(Nr * 4);
    int*   rowptr = (int*)alloc((Nr + 256) * 4);
    int*   cursor = (int*)alloc(Nr * 4);
    int*   bsum   = (int*)alloc(1024);
    int*   csr    = (int*)alloc((size_t)E * 4);
    short* wt     = (short*)alloc((size_t)NLAYERS * 131072 * 2);  // 2 MB folded conv weights
    short* w1t    = (short*)alloc((size_t)DH * DIN * 2);          // lin1^T
    short* w2t    = (short*)alloc((size_t)DOUT * DH * 2);         // lin2^T
    short* xb     = (short*)alloc((size_t)N * DIN * 2);           // x as bf16
    bf16*  agg    = (bf16*)alloc(NDH * 2);
    bf16*  x0     = (bf16*)alloc(NDH * 2);
    bf16*  h      = (bf16*)alloc(NDH * 2);

    dim3 blk(256);
    int nbN = (N + 255) / 256;
    dim3 gN(nbN);
    dim3 gE((E + 255) / 256);
    dim3 gB((N + 127) / 128);
    dim3 gG((N + 3) / 4);
    dim3 gElem((unsigned)((NDH + 255) / 256));
    dim3 gTW(8, 8, 16);
    dim3 bTW(32, 8);
    dim3 blk512(512);

    k_detect<<<1, 256, 0, stream>>>((const unsigned int*)x, flag);
    k_init_cnt<<<gN, blk, 0, stream>>>(cnt, N);
    k_count<<<gE, blk, 0, stream>>>(cols, cnt, E);
    k_dis<<<gN, blk, 0, stream>>>(cnt, dis, N);
    k_scan1<<<gN, blk, 0, stream>>>(cnt, rowptr, bsum, N);
    k_scan2<<<1, 256, 0, stream>>>(bsum, nbN);
    k_scan3<<<gN, blk, 0, stream>>>(rowptr, bsum, N);
    k_cursor<<<gN, blk, 0, stream>>>(rowptr, cursor, N);
    k_fill<<<gE, blk, 0, stream>>>(rows, cols, cursor, csr, E);
    k_zero_stats<<<1, 64, 0, stream>>>(stats);
    k_transw2<<<gTW, bTW, 0, stream>>>(conv_w1, conv_w2, flag, wt);
    k_transw_lin<<<dim3(DH / 32, DIN / 32), bTW, 0, stream>>>(lin1_w, flag, w1t, DIN, DH);
    k_transw_lin<<<dim3(DOUT / 32, DH / 32), bTW, 0, stream>>>(lin2_w, flag, w2t, DH, DOUT);
    k_convx<<<dim3((unsigned)(((size_t)N * DIN + 255) / 256)), blk, 0, stream>>>(x, flag, xb, N * DIN);

    // lin1: x0 = relu(x @ lin1_w + b)
    gemm_mfma<DH, DIN, 0><<<gB, blk512, 0, stream>>>(xb, w1t, lin1_b, flag, x0, N);

    const float invTotal = 1.0f / ((float)N * (float)DH);
    for (int l = 0; l < NLAYERS; l++) {
        const bf16* hsrc = (l == 0) ? x0 : h;
        size_t loff = (l == 0) ? 0 : (size_t)(l - 1) * DH;
        const float* st = (l == 0) ? stats : stats + 2 * (l - 1);
        k_gather2<<<gG, blk, 0, stream>>>(rowptr, csr, dis, hsrc, agg,
                                          gam, bet, loff, st, invTotal,
                                          l > 0 ? 1 : 0, flag, N);
        gemm_layer3<<<gB, blk512, 0, stream>>>(agg, x0, wt + (size_t)l * 131072,
                                               h, stats + 2 * l, N);
    }
    // final LN + relu in place, then lin2
    k_applyT<<<gElem, blk, 0, stream>>>(h, stats + 2 * (NLAYERS - 1), invTotal,
                                        gam, bet, (size_t)(NLAYERS - 1) * DH,
                                        flag, (int)NDH);
    gemm_mfma<DOUT, DH, 1><<<gB, blk512, 0, stream>>>((const short*)h, w2t, lin2_b,
                                                      flag, d_out, N);
}